// Round 2
// baseline (2299.231 us; speedup 1.0000x reference)
//
#include <hip/hip_runtime.h>

// Problem constants (from reference)
#define T_STEPS 100
#define BATCH   32
#define NIN     512
#define NN      2048
#define AREAS   2

// ALPHA = float(np.exp(-1e-3/1e-2)) as f64, then cast to f32 at use-site,
// exactly mirroring numpy's weak-scalar (NEP 50) behavior: f32_arr * py_float
// computes in f32 with the scalar rounded f64->f32.
#define ALPHA_D 0.9048374180359595

// ---------------------------------------------------------------------------
// k0: Poisson input spikes for ALL timesteps (pure function of rates/noise).
// f32 semantics: spike = noise < f32(rate * f32(0.001)), matching np f32 ref.
// Writes f32 Xi to d_out[0..T*B*NIN) and per-(t,b) transposed bitmasks:
// xi_mask[(t*32+b)*16 + (i>>5)] bit (i&31)  -> ascending-i walk per batch.
__global__ __launch_bounds__(256)
void k0_xi(const float* __restrict__ rates, const float* __restrict__ noise,
           float* __restrict__ outXi, unsigned* __restrict__ xi_mask)
{
    int el = blockIdx.x * 256 + threadIdx.x;      // exact grid: 1,638,400
    float r = rates[el], nz = noise[el];
    float p = __fmul_rn(r, 0.001f);               // f32 mul, no contraction
    int spike = (nz < p) ? 1 : 0;
    outXi[el] = (float)spike;
    if (spike) {
        int t = el >> 14;            // / (B*NIN)=16384
        int b = (el >> 9) & 31;
        int i = el & (NIN - 1);
        atomicOr(&xi_mask[(t * 32 + b) * 16 + (i >> 5)], 1u << (i & 31));
    }
}

// ---------------------------------------------------------------------------
// k_step: ONE kernel per timestep. grid (mchunk:8, b:32, a:2) x 256 threads.
// Block owns one (a,b,mrange of 256 cols). Decodes per-b active lists
// (ff rows ascending i; rec rows ascending (s,n) lex == rr=s*2048+n) into
// LDS, then each thread serially accumulates f32 adds in EXACTLY numpy's
// einsum order, does the LIF update with explicit rn ops (no fma), emits
// spike + next-step bitmask. 3-buffer mask rotation: read prev, atomicOr
// next, zero clear (untouched by anyone else this step).
__global__ __launch_bounds__(256)
void k_step(const float* __restrict__ Win, const float* __restrict__ Wrec,
            const unsigned* __restrict__ xi_mask,   // [(t*32+b)*16 + w]
            const unsigned* __restrict__ smask_prev,// [b*128 + w]
            unsigned* __restrict__ smask_next,
            unsigned* __restrict__ smask_clear,
            float* __restrict__ V,                  // f32 [A][B][N]
            float* __restrict__ outS,               // out + T*B*NIN
            int t)
{
    const int tid = threadIdx.x;
    const int mc  = blockIdx.x;      // 0..7
    const int b   = blockIdx.y;      // 0..31
    const int a   = blockIdx.z;      // 0..1
    const int m   = mc * 256 + tid;  // 0..2047

    // zero the clear-buffer (4096 words over 512 blocks -> 8 words/block)
    {
        int fb = ((a * 32 + b) * 8 + mc);
        if (tid < 8) smask_clear[fb * 8 + tid] = 0u;
    }

    __shared__ unsigned short lff[NIN];        // active ff rows (i)
    __shared__ unsigned short lrec[AREAS * NN];// active rec rows (rr=s*2048+n)
    __shared__ int pc[144], woff[144];
    __shared__ int cnt_ff, cnt_rec;

    unsigned myw = 0u;
    if (tid < 144)
        myw = (tid < 16) ? xi_mask[(t * 32 + b) * 16 + tid]
                         : smask_prev[b * 128 + (tid - 16)];
    if (tid < 144) pc[tid] = __popc(myw);
    __syncthreads();
    if (tid == 0) {
        int s = 0;
        for (int w = 0; w < 16; ++w)  { woff[w] = s; s += pc[w]; }
        cnt_ff = s;
        s = 0;
        for (int w = 16; w < 144; ++w){ woff[w] = s; s += pc[w]; }
        cnt_rec = s;
    }
    __syncthreads();
    if (tid < 144 && myw) {
        int off = woff[tid];
        unsigned w = myw;
        if (tid < 16) {
            int base = tid * 32;
            while (w) { int p = __ffs(w) - 1; lff[off++] = (unsigned short)(base + p); w &= w - 1; }
        } else {
            int base = (tid - 16) * 32;
            while (w) { int p = __ffs(w) - 1; lrec[off++] = (unsigned short)(base + p); w &= w - 1; }
        }
    }
    __syncthreads();

    const int nff = cnt_ff, nrec = cnt_rec;

    // ---- feedforward: acc over active i ASCENDING, sequential f32 adds ----
    const float* __restrict__ Wa = Win + ((size_t)a * NIN << 11) + m;
    float accf = 0.0f;
    for (int j = 0; j < nff; ++j)
        accf += Wa[(size_t)lff[j] << 11];      // pure adds: order-exact

    // ---- recurrent: acc over active (s,n) lex ASCENDING ----
    const float* __restrict__ Wr = Wrec + m;
    float accr = 0.0f;
    for (int j = 0; j < nrec; ++j) {
        int rr = lrec[j];                       // s*2048+n
        size_t idx = (((size_t)(rr >> 11) * 2 + a) << 22) + ((size_t)(rr & (NN - 1)) << 11);
        accr += Wr[idx];
    }

    // ---- LIF update, numpy f32 op-for-op ----
    int vi = ((a * 32) + b) * NN + m;
    int rr_self = (a << 11) | m;
    unsigned xd = (smask_prev[b * 128 + (rr_self >> 5)] >> (rr_self & 31)) & 1u;
    float I  = __fadd_rn(accf, accr);           // einsum1 + einsum2
    float v  = __fmul_rn((float)ALPHA_D, V[vi]);// ALPHA*V (f32, unfused)
    if (xd) v = 0.0f;                           // *(1-Xd): exact
    float vn = __fadd_rn(v, I);                 // + I (unfused)
    V[vi] = vn;
    int S = (vn >= 1.0f) ? 1 : 0;
    outS[(size_t)a * (T_STEPS * BATCH * NN) + (((size_t)t * BATCH + b) << 11) + m]
        = (float)S;
    if (S) atomicOr(&smask_next[b * 128 + (rr_self >> 5)], 1u << (rr_self & 31));
}

// ---------------------------------------------------------------------------
extern "C" void kernel_launch(void* const* d_in, const int* in_sizes, int n_in,
                              void* d_out, int out_size, void* d_ws, size_t ws_size,
                              hipStream_t stream)
{
    const float* rates = (const float*)d_in[0];
    const float* noise = (const float*)d_in[1];
    const float* Win   = (const float*)d_in[2];
    const float* Wrec  = (const float*)d_in[3];
    float* out = (float*)d_out;

    // workspace layout (bytes):
    //   [0, 204800)            xi_mask uint32[T][B][16]   (transposed bitmask)
    //   [204800, 253952)       smask   uint32[3][B][128]  (3-buffer rotation)
    //   [253952, 778240)       V       float[A][B][N]
    char* ws = (char*)d_ws;
    unsigned* xi_mask = (unsigned*)ws;
    unsigned* smask   = (unsigned*)(ws + 204800);
    float*    V       = (float*)(ws + 253952);

    hipMemsetAsync(d_ws, 0, 778240, stream);    // zero masks + V

    k0_xi<<<6400, 256, 0, stream>>>(rates, noise, out, xi_mask);

    float* outS = out + (size_t)T_STEPS * BATCH * NIN;
    const int MW = BATCH * 128;                 // words per smask buffer
    for (int t = 0; t < T_STEPS; ++t) {
        unsigned* prev  = smask + (t % 3) * MW;
        unsigned* next  = smask + ((t + 1) % 3) * MW;
        unsigned* clear = smask + ((t + 2) % 3) * MW;
        k_step<<<dim3(8, 32, 2), 256, 0, stream>>>(
            Win, Wrec, xi_mask, prev, next, clear, V, outS, t);
    }
}

// Round 3
// 2136.886 us; speedup vs baseline: 1.0760x; 1.0760x over previous
//
#include <hip/hip_runtime.h>

// Problem constants (from reference)
#define T_STEPS 100
#define BATCH   32
#define NIN     512
#define NN      2048
#define AREAS   2

// ALPHA = float(np.exp(-1e-3/1e-2)); cast to f32 at use-site (NEP-50 weak scalar).
#define ALPHA_D 0.9048374180359595

// ---------------------------------------------------------------------------
// k0: Poisson input spikes for ALL timesteps. f32 compare semantics.
// Writes f32 Xi to d_out[0..T*B*NIN) and per-(t,b) bitmasks
// xi_mask[(t*32+b)*16 + (i>>5)] bit (i&31) -> ascending-i walk per batch.
__global__ __launch_bounds__(256)
void k0_xi(const float* __restrict__ rates, const float* __restrict__ noise,
           float* __restrict__ outXi, unsigned* __restrict__ xi_mask)
{
    int el = blockIdx.x * 256 + threadIdx.x;      // exact grid: 1,638,400
    float r = rates[el], nz = noise[el];
    float p = __fmul_rn(r, 0.001f);
    int spike = (nz < p) ? 1 : 0;
    outXi[el] = (float)spike;
    if (spike) {
        int t = el >> 14;
        int b = (el >> 9) & 31;
        int i = el & (NIN - 1);
        atomicOr(&xi_mask[(t * 32 + b) * 16 + (i >> 5)], 1u << (i & 31));
    }
}

// ---------------------------------------------------------------------------
// k_ff: precompute feedforward currents I_ff[t][a][b][n] for ALL timesteps.
// grid (cg:128, a:2) x 256. Block stages Win[a][0..511][cg*16..+16) in LDS
// (32 KB), then each thread serially accumulates its (t,b) pairs over active
// i ASCENDING (bit-exact vs numpy einsum order; pure f32 adds, no fma).
__global__ __launch_bounds__(256)
void k_ff(const float* __restrict__ Win, const unsigned* __restrict__ xi_mask,
          float* __restrict__ Iff)
{
    const int tid = threadIdx.x;
    const int cg  = blockIdx.x;      // 0..127 (16 cols each)
    const int a   = blockIdx.y;      // 0..1

    __shared__ float Ws[NIN][16];    // 32 KB

    const float* Wbase = Win + ((size_t)a * NIN << 11) + (cg << 4);
    for (int j = tid; j < NIN * 4; j += 256) {       // float4 tiles
        int row = j >> 2, c4 = j & 3;
        float4 v = *(const float4*)(Wbase + ((size_t)row << 11) + (c4 << 2));
        *(float4*)&Ws[row][c4 << 2] = v;
    }
    __syncthreads();

    for (int p = tid; p < T_STEPS * BATCH; p += 256) {
        float4 A0 = {0,0,0,0}, A1 = {0,0,0,0}, A2 = {0,0,0,0}, A3 = {0,0,0,0};
        const unsigned* mp = xi_mask + p * 16;
        for (int w = 0; w < 16; ++w) {
            unsigned mw = mp[w];
            int base_i = w << 5;
            while (mw) {
                int i = base_i + (__ffs(mw) - 1);
                mw &= mw - 1;
                const float4* ws = (const float4*)&Ws[i][0];
                float4 w0 = ws[0], w1 = ws[1], w2 = ws[2], w3 = ws[3];
                A0.x += w0.x; A0.y += w0.y; A0.z += w0.z; A0.w += w0.w;
                A1.x += w1.x; A1.y += w1.y; A1.z += w1.z; A1.w += w1.w;
                A2.x += w2.x; A2.y += w2.y; A2.z += w2.z; A2.w += w2.w;
                A3.x += w3.x; A3.y += w3.y; A3.z += w3.z; A3.w += w3.w;
            }
        }
        int t = p >> 5, b = p & 31;
        float* op = Iff + ((((size_t)t * 2 + a) * 32 + b) << 11) + (cg << 4);
        ((float4*)op)[0] = A0; ((float4*)op)[1] = A1;
        ((float4*)op)[2] = A2; ((float4*)op)[3] = A3;
    }
}

// ---------------------------------------------------------------------------
// k_step: one kernel per timestep, RECURRENT part only + LIF.
// grid (mc:8, b:32, a:2) x 256. Parallel shuffle prefix-scan builds the
// per-b active rec-row list (ascending rr = s*2048+n == numpy lex order),
// each thread serially accumulates f32 adds, I = Iff + accr, LIF, spikes.
__global__ __launch_bounds__(256)
void k_step(const float* __restrict__ Wrec,
            const unsigned* __restrict__ smask_prev,// [b*128 + w]
            unsigned* __restrict__ smask_next,
            unsigned* __restrict__ smask_clear,
            const float* __restrict__ Iff,          // [t][a][b][n]
            float* __restrict__ V,                  // f32 [A][B][N]
            float* __restrict__ outS,               // out + T*B*NIN
            int t)
{
    const int tid = threadIdx.x;
    const int mc  = blockIdx.x;      // 0..7
    const int b   = blockIdx.y;      // 0..31
    const int a   = blockIdx.z;      // 0..1
    const int m   = mc * 256 + tid;  // 0..2047

    // zero next-next-step mask buffer (512 blocks x 8 words = 4096)
    {
        int fb = ((a * 32 + b) * 8 + mc);
        if (tid < 8) smask_clear[fb * 8 + tid] = 0u;
    }

    __shared__ unsigned short lrec[AREAS * NN];   // active rec rows, 8 KB
    __shared__ unsigned mws[128];
    __shared__ int base[128];
    __shared__ int cnt_rec;

    if (tid < 128) mws[tid] = smask_prev[b * 128 + tid];
    __syncthreads();
    if (tid < 64) {                  // wave-0 shuffle prefix scan, 2 words/lane
        int c0 = __popc(mws[2 * tid]), c1 = __popc(mws[2 * tid + 1]);
        int c = c0 + c1, incl = c;
        #pragma unroll
        for (int d = 1; d < 64; d <<= 1) {
            int v = __shfl_up(incl, d, 64);
            if (tid >= d) incl += v;
        }
        base[2 * tid]     = incl - c;
        base[2 * tid + 1] = incl - c1;
        if (tid == 63) cnt_rec = incl;
    }
    __syncthreads();
    if (tid < 128 && mws[tid]) {
        int off = base[tid];
        unsigned w = mws[tid];
        int bb = tid << 5;
        while (w) { int p = __ffs(w) - 1; lrec[off++] = (unsigned short)(bb + p); w &= w - 1; }
    }
    __syncthreads();

    const int nrec = cnt_rec;

    // ---- recurrent: acc over active (s,n) lex ASCENDING, serial f32 adds ---
    const float* __restrict__ Wr = Wrec + m;
    auto off_of = [&](int rr) -> size_t {
        return (((size_t)(rr >> 11) * 2 + a) << 22) + ((size_t)(rr & (NN - 1)) << 11);
    };
    float accr = 0.0f;
    int j = 0;
    for (; j + 4 <= nrec; j += 4) {
        int r0 = lrec[j], r1 = lrec[j+1], r2 = lrec[j+2], r3 = lrec[j+3];
        float w0 = Wr[off_of(r0)], w1 = Wr[off_of(r1)],
              w2 = Wr[off_of(r2)], w3 = Wr[off_of(r3)];
        accr = __fadd_rn(__fadd_rn(__fadd_rn(__fadd_rn(accr, w0), w1), w2), w3);
    }
    for (; j < nrec; ++j) accr = __fadd_rn(accr, Wr[off_of(lrec[j])]);

    // ---- LIF update, numpy f32 op-for-op ----
    float accf = Iff[((((size_t)t * 2 + a) * 32 + b) << 11) + m];
    int vi = ((a * 32) + b) * NN + m;
    int rr_self = (a << 11) | m;
    unsigned xd = (smask_prev[b * 128 + (rr_self >> 5)] >> (rr_self & 31)) & 1u;
    float I  = __fadd_rn(accf, accr);
    float v  = __fmul_rn((float)ALPHA_D, V[vi]);
    if (xd) v = 0.0f;
    float vn = __fadd_rn(v, I);
    V[vi] = vn;
    int S = (vn >= 1.0f) ? 1 : 0;
    outS[(size_t)a * (T_STEPS * BATCH * NN) + (((size_t)t * BATCH + b) << 11) + m]
        = (float)S;
    if (S) atomicOr(&smask_next[b * 128 + (rr_self >> 5)], 1u << (rr_self & 31));
}

// ---------------------------------------------------------------------------
extern "C" void kernel_launch(void* const* d_in, const int* in_sizes, int n_in,
                              void* d_out, int out_size, void* d_ws, size_t ws_size,
                              hipStream_t stream)
{
    const float* rates = (const float*)d_in[0];
    const float* noise = (const float*)d_in[1];
    const float* Win   = (const float*)d_in[2];
    const float* Wrec  = (const float*)d_in[3];
    float* out = (float*)d_out;

    // workspace layout (bytes):
    //   [0, 204800)          xi_mask uint32[T][B][16]
    //   [204800, 253952)     smask   uint32[3][B][128]
    //   [253952, 778240)     V       float[A][B][N]
    //   [778240, +52428800)  Iff     float[T][A][B][N]
    char* ws = (char*)d_ws;
    unsigned* xi_mask = (unsigned*)ws;
    unsigned* smask   = (unsigned*)(ws + 204800);
    float*    V       = (float*)(ws + 253952);
    float*    Iff     = (float*)(ws + 778240);

    hipMemsetAsync(d_ws, 0, 778240, stream);    // zero masks + V

    k0_xi<<<6400, 256, 0, stream>>>(rates, noise, out, xi_mask);
    k_ff<<<dim3(128, 2), 256, 0, stream>>>(Win, xi_mask, Iff);

    float* outS = out + (size_t)T_STEPS * BATCH * NIN;
    const int MW = BATCH * 128;                 // words per smask buffer
    for (int t = 0; t < T_STEPS; ++t) {
        unsigned* prev  = smask + (t % 3) * MW;
        unsigned* next  = smask + ((t + 1) % 3) * MW;
        unsigned* clear = smask + ((t + 2) % 3) * MW;
        k_step<<<dim3(8, 32, 2), 256, 0, stream>>>(
            Wrec, prev, next, clear, Iff, V, outS, t);
    }
}